// Round 19
// baseline (72.545 us; speedup 1.0000x reference)
//
#include <hip/hip_runtime.h>

#define B_ 4
#define N_ 512
#define D_ 768
#define A_ 128

typedef short bf16x8 __attribute__((ext_vector_type(8)));
typedef ushort u16x8 __attribute__((ext_vector_type(8)));
typedef ushort u16x4 __attribute__((ext_vector_type(4)));
typedef float f32x4 __attribute__((ext_vector_type(4)));

__device__ __forceinline__ ushort f2h(float x) {  // f32 -> bf16 bits, RNE
  uint u = __builtin_bit_cast(uint, x);
  return (ushort)((u + 0x7fffu + ((u >> 16) & 1u)) >> 16);
}
__device__ __forceinline__ float h2f(ushort h) {
  uint u = ((uint)h) << 16;
  return __builtin_bit_cast(float, u);
}
__device__ __forceinline__ bf16x8 ld8(const ushort* p) {
  return *(const bf16x8*)p;
}
#define MFMA(a, b, c) __builtin_amdgcn_mfma_f32_16x16x32_bf16(a, b, c, 0, 0, 0)

// ---------------------------------------------------------------------------
// k0: fused prep (+ uvec = -2*v write). Unchanged from R18.
// ---------------------------------------------------------------------------
__global__ __launch_bounds__(256) void k0_prep(
    const float* __restrict__ M, const float* __restrict__ W1,
    const float* __restrict__ W2, const float* __restrict__ vw,
    ushort* __restrict__ Mr_h, ushort* __restrict__ Mr_l,
    ushort* __restrict__ Mt_h, ushort* __restrict__ Mt_l,
    ushort* __restrict__ Wt_h, ushort* __restrict__ Wt_l,
    float* __restrict__ uvec) {
  __shared__ ushort lds_h[64][40];
  __shared__ ushort lds_l[64][40];
  const int t = threadIdx.x;
  const int bid = blockIdx.x;
  if (bid < 768) {  // ---- M part ----
    const int dq = bid % 12;
    const int rest = bid / 12;
    const int d0 = dq * 64;
    const int n0 = (rest & 15) * 32;
    const int b = rest >> 4;
    const int n = t >> 3;          // 0..31
    const int dg = (t & 7) * 8;    // 0..56
    const size_t roff = ((size_t)(b * N_ + n0 + n)) * D_ + d0 + dg;
    const float4 v0 = *(const float4*)(M + roff);
    const float4 v1 = *(const float4*)(M + roff + 4);
    const float x[8] = {v0.x, v0.y, v0.z, v0.w, v1.x, v1.y, v1.z, v1.w};
    u16x8 vh, vl;
#pragma unroll
    for (int e = 0; e < 8; ++e) {
      ushort h = f2h(x[e]);
      ushort l = f2h(x[e] - h2f(h));
      vh[e] = h;
      vl[e] = l;
      lds_h[dg + e][n] = h;
      lds_l[dg + e][n] = l;
    }
    *(u16x8*)(Mr_h + roff) = vh;
    *(u16x8*)(Mr_l + roff) = vl;
    __syncthreads();
    const int dd = t >> 2;          // 0..63
    const int ng = (t & 3) * 8;     // 0..24
    const size_t toff = ((size_t)b * D_ + d0 + dd) * N_ + n0 + ng;
    *(u16x8*)(Mt_h + toff) = *(const u16x8*)(&lds_h[dd][ng]);
    *(u16x8*)(Mt_l + toff) = *(const u16x8*)(&lds_l[dd][ng]);
  } else {  // ---- W part ----
    const int c = t;
    const int k0 = (bid - 768) * 8;
    const float* __restrict__ Wp = (c < A_) ? W1 : W2;
    const int cc = c & (A_ - 1);
    u16x8 vh, vl;
#pragma unroll
    for (int e = 0; e < 8; ++e) {
      float x = Wp[(size_t)(k0 + e) * A_ + cc];
      ushort h = f2h(x);
      vh[e] = h;
      vl[e] = f2h(x - h2f(h));
    }
    *(u16x8*)(Wt_h + (size_t)c * D_ + k0) = vh;
    *(u16x8*)(Wt_l + (size_t)c * D_ + k0) = vl;
    if (bid == 768 && c < A_) uvec[c] = -2.f * vw[c];
  }
}

// ---------------------------------------------------------------------------
// k1 v5: M @ [W1|W2] -> EXPONENTIALS. OCCUPANCY: 8-wave K-split (wave w
// owns 96 K = 3 K-steps), 512-thr blocks, 2 blocks/CU -> 4 waves/SIMD
// (was 2 -- the v15 lesson applied). Single-buffered frags (~65 VGPR);
// TLP hides load latency. LDS reduce [8][32][33] = 33.8 KB.
// E1 f32 out; E2 bf16 out (as R18).
// ---------------------------------------------------------------------------
__global__ __launch_bounds__(512, 4) void k1_mfma(
    const ushort* __restrict__ Mr_h, const ushort* __restrict__ Mr_l,
    const ushort* __restrict__ Wt_h, const ushort* __restrict__ Wt_l,
    const float* __restrict__ b1, const float* __restrict__ b2,
    float* __restrict__ w1e, ushort* __restrict__ w2e) {
  __shared__ float l_red[8][32][33];  // 33.8 KB
  const int t = threadIdx.x;
  const int l = t & 63;
  const int w = t >> 6;   // 0..7
  const int r = l & 15, g = l >> 4;
  const int row0 = blockIdx.x * 32;
  const int cb = blockIdx.y * 32;
  const int kbase = w * 96;  // wave-private K-range (3 K-steps of 32)
  const size_t oA = (size_t)(row0 + r) * D_ + kbase + g * 8;
  const size_t oA2 = oA + (size_t)16 * D_;
  const size_t oB = (size_t)(cb + r) * D_ + kbase + g * 8;
  const size_t oB2 = oB + (size_t)16 * D_;
  f32x4 acc[2][2] = {};
#pragma unroll
  for (int kt = 0; kt < 3; ++kt) {
    const int k0 = kt * 32;
    bf16x8 A0 = ld8(Mr_h + oA + k0);
    bf16x8 A1 = ld8(Mr_h + oA2 + k0);
    bf16x8 A2 = ld8(Mr_l + oA + k0);
    bf16x8 A3 = ld8(Mr_l + oA2 + k0);
    bf16x8 B0 = ld8(Wt_h + oB + k0);
    bf16x8 B1 = ld8(Wt_h + oB2 + k0);
    bf16x8 B2 = ld8(Wt_l + oB + k0);
    bf16x8 B3 = ld8(Wt_l + oB2 + k0);
    acc[0][0] = MFMA(A0, B0, acc[0][0]);
    acc[0][0] = MFMA(A0, B2, acc[0][0]);
    acc[0][0] = MFMA(A2, B0, acc[0][0]);
    acc[0][1] = MFMA(A0, B1, acc[0][1]);
    acc[0][1] = MFMA(A0, B3, acc[0][1]);
    acc[0][1] = MFMA(A2, B1, acc[0][1]);
    acc[1][0] = MFMA(A1, B0, acc[1][0]);
    acc[1][0] = MFMA(A1, B2, acc[1][0]);
    acc[1][0] = MFMA(A3, B0, acc[1][0]);
    acc[1][1] = MFMA(A1, B1, acc[1][1]);
    acc[1][1] = MFMA(A1, B3, acc[1][1]);
    acc[1][1] = MFMA(A3, B1, acc[1][1]);
  }
#pragma unroll
  for (int fi = 0; fi < 2; ++fi)
#pragma unroll
    for (int fj = 0; fj < 2; ++fj)
#pragma unroll
      for (int rr = 0; rr < 4; ++rr)
        l_red[w][fi * 16 + g * 4 + rr][fj * 16 + r] = acc[fi][fj][rr];
  __syncthreads();

  const float SC = 2.8853900817779268f;  // 2*log2(e): e^{2x} = 2^{SC*x}
  const int b = row0 >> 9;
  const int n0 = row0 & (N_ - 1);
  if (cb < A_) {  // E1: w1e[row][col] f32, col-fast coalesced
#pragma unroll
    for (int k = 0; k < 2; ++k) {
      const int idx = t + k * 512;
      const int row = idx >> 5;
      const int col = idx & 31;
      float v = 0.f;
#pragma unroll
      for (int s = 0; s < 8; ++s) v += l_red[s][row][col];
      v = (v + b1[cb + col]) * SC;
      w1e[(size_t)(row0 + row) * A_ + cb + col] = __builtin_amdgcn_exp2f(v);
    }
  } else {  // E2: w2e[(b*128 + a)*512 + n] BF16, row(n)-fast
#pragma unroll
    for (int k = 0; k < 2; ++k) {
      const int idx = t + k * 512;
      const int row = idx & 31;   // n
      const int col = idx >> 5;   // a-col within tile
      float v = 0.f;
#pragma unroll
      for (int s = 0; s < 8; ++s) v += l_red[s][row][col];
      v = (v + b2[cb - A_ + col]) * SC;
      w2e[(size_t)(b * A_ + cb - A_ + col) * N_ + n0 + row] =
          f2h(__builtin_amdgcn_exp2f(v));
    }
  }
}

// ---------------------------------------------------------------------------
// k2 v18: barrier-free streaming scores (unchanged from R18).
// ---------------------------------------------------------------------------
__global__ __launch_bounds__(512, 8) void k2_scores(
    const float* __restrict__ w1e, const ushort* __restrict__ w2e,
    const float* __restrict__ uvec, const int* __restrict__ mask,
    const float* __restrict__ vw, ushort* __restrict__ ah,
    ushort* __restrict__ al) {
  __shared__ float l_red[2][4];
  __shared__ float l_sum[2][4];
  const int t = threadIdx.x;
  const int lane = t & 63;
  const int w = t >> 6;   // 0..7
  const int r = w >> 2;   // row in block 0..1
  const int q = w & 3;    // j-quarter
  const int i0 = blockIdx.x * 2;
  const int b = i0 >> 9;
  const int i = i0 + r;
  const int iu = __builtin_amdgcn_readfirstlane(i);
  const float* __restrict__ w1row = w1e + (size_t)iu * A_;  // scalar loads

  float vs = vw[lane] + vw[64 + lane];  // Vsum via butterfly
#pragma unroll
  for (int off = 32; off; off >>= 1) vs += __shfl_xor(vs, off);

  const int jq = q * 128 + lane * 2;  // this lane's 2 j columns
  const ushort* __restrict__ w2p = w2e + (size_t)b * A_ * N_ + jq;

  float sx = 0.f, sy = 0.f;
#pragma unroll 1
  for (int cc = 0; cc < 8; ++cc) {
#pragma unroll 1
    for (int aa = 0; aa < 4; ++aa) {
      const float4 wa = *(const float4*)(w1row + cc * 16 + aa * 4);  // s_load
      const float4 uu = *(const float4*)(uvec + cc * 16 + aa * 4);   // s_load
      const float wa_[4] = {wa.x, wa.y, wa.z, wa.w};
      const float uu_[4] = {uu.x, uu.y, uu.z, uu.w};
      uint xr_[4];
#pragma unroll
      for (int e = 0; e < 4; ++e)
        xr_[e] = *(const uint*)(w2p + (size_t)(cc * 16 + aa * 4 + e) * N_);
#pragma unroll
      for (int e = 0; e < 4; ++e) {
        const float wx = wa_[e];
        const float ux = uu_[e];
        const float x0 = __builtin_bit_cast(float, xr_[e] << 16);
        const float x1 = __builtin_bit_cast(float, xr_[e] & 0xffff0000u);
        sx = fmaf(ux, __builtin_amdgcn_rcpf(fmaf(wx, x0, 1.f)), sx);
        sy = fmaf(ux, __builtin_amdgcn_rcpf(fmaf(wx, x1, 1.f)), sy);
      }
    }
  }

  const float NEG = -3.402823466e38f;  // np.finfo(f32).min
  const int2 mk = *(const int2*)(mask + (size_t)i * N_ + jq);
  sx = mk.x ? (vs + sx) : NEG;
  sy = mk.y ? (vs + sy) : NEG;

  float rmax = fmaxf(sx, sy);
#pragma unroll
  for (int off = 32; off; off >>= 1) rmax = fmaxf(rmax, __shfl_xor(rmax, off));
  if (lane == 0) l_red[r][q] = rmax;
  __syncthreads();
  rmax = fmaxf(fmaxf(l_red[r][0], l_red[r][1]),
               fmaxf(l_red[r][2], l_red[r][3]));

  const float L2E = 1.4426950408889634f;
  // all-masked row: s-rmax = 0 -> 1 -> uniform 1/512 (ref match);
  // masked in live row: (NEG-rmax)*L2E -> -inf -> exp2 = 0 exactly.
  sx = __builtin_amdgcn_exp2f((sx - rmax) * L2E);
  sy = __builtin_amdgcn_exp2f((sy - rmax) * L2E);
  float psum = sx + sy;
#pragma unroll
  for (int off = 32; off; off >>= 1) psum += __shfl_xor(psum, off);
  if (lane == 0) l_sum[r][q] = psum;
  __syncthreads();
  const float inv = __builtin_amdgcn_rcpf(
      (l_sum[r][0] + l_sum[r][1]) + (l_sum[r][2] + l_sum[r][3]));

  const float p0 = sx * inv;
  const float p1 = sy * inv;
  const ushort h0 = f2h(p0);
  const ushort h1 = f2h(p1);
  const ushort g0 = f2h(p0 - h2f(h0));
  const ushort g1 = f2h(p1 - h2f(h1));
  const size_t base = (size_t)i * N_ + jq;
  *(uint*)(ah + base) = (uint)h0 | ((uint)h1 << 16);
  *(uint*)(al + base) = (uint)g0 | ((uint)g1 << 16);
}

// ---------------------------------------------------------------------------
// k3 v5: out[b] = attn[b] @ M[b]. OCCUPANCY: 8 waves = 2 row-halves x 4
// j-slices; wave = 32 rows x 32 d x 128 j (48 MFMA). Grid 768 x 512 thr ->
// 3 blocks/CU -> 6 waves/SIMD (was 3). Single-buffered frags (~65 VGPR,
// launch_bounds(512,6)). LDS reduce [2][4][32][33] = 33.8 KB.
// ---------------------------------------------------------------------------
__global__ __launch_bounds__(512, 6) void k3_mfma(
    const ushort* __restrict__ ah, const ushort* __restrict__ al,
    const ushort* __restrict__ Mt_h, const ushort* __restrict__ Mt_l,
    float* __restrict__ out) {
  __shared__ float l_red[2][4][32][33];  // 33.8 KB
  const int t = threadIdx.x;
  const int l = t & 63;
  const int w = t >> 6;    // 0..7
  const int hh = w >> 2;   // row-half 0/1
  const int jw = w & 3;    // j-slice
  const int r = l & 15, g = l >> 4;
  const int row0 = blockIdx.x * 64;    // global row b*N+i (64 | 512)
  const int d0 = blockIdx.y * 32;
  const int b = row0 >> 9;
  const int rbase = row0 + hh * 32;
  const int jbase = jw * 128;  // wave-private j-range (4 K-steps of 32)
  const ushort* __restrict__ Bh = Mt_h + (size_t)b * D_ * N_;
  const ushort* __restrict__ Bl = Mt_l + (size_t)b * D_ * N_;
  const size_t oA = (size_t)(rbase + r) * N_ + jbase + g * 8;
  const size_t oA2 = oA + (size_t)16 * N_;
  const size_t oB = (size_t)(d0 + r) * N_ + jbase + g * 8;
  const size_t oB2 = oB + (size_t)16 * N_;
  f32x4 acc[2][2] = {};
#pragma unroll
  for (int kt = 0; kt < 4; ++kt) {
    const int j0 = kt * 32;
    bf16x8 A0 = ld8(ah + oA + j0);
    bf16x8 A1 = ld8(ah + oA2 + j0);
    bf16x8 A2 = ld8(al + oA + j0);
    bf16x8 A3 = ld8(al + oA2 + j0);
    bf16x8 B0 = ld8(Bh + oB + j0);
    bf16x8 B1 = ld8(Bh + oB2 + j0);
    bf16x8 B2 = ld8(Bl + oB + j0);
    bf16x8 B3 = ld8(Bl + oB2 + j0);
    acc[0][0] = MFMA(A0, B0, acc[0][0]);
    acc[0][0] = MFMA(A0, B2, acc[0][0]);
    acc[0][0] = MFMA(A2, B0, acc[0][0]);
    acc[0][1] = MFMA(A0, B1, acc[0][1]);
    acc[0][1] = MFMA(A0, B3, acc[0][1]);
    acc[0][1] = MFMA(A2, B1, acc[0][1]);
    acc[1][0] = MFMA(A1, B0, acc[1][0]);
    acc[1][0] = MFMA(A1, B2, acc[1][0]);
    acc[1][0] = MFMA(A3, B0, acc[1][0]);
    acc[1][1] = MFMA(A1, B1, acc[1][1]);
    acc[1][1] = MFMA(A1, B3, acc[1][1]);
    acc[1][1] = MFMA(A3, B1, acc[1][1]);
  }
#pragma unroll
  for (int fi = 0; fi < 2; ++fi)
#pragma unroll
    for (int fd = 0; fd < 2; ++fd)
#pragma unroll
      for (int rr = 0; rr < 4; ++rr)
        l_red[hh][jw][fi * 16 + g * 4 + rr][fd * 16 + r] = acc[fi][fd][rr];
  __syncthreads();
#pragma unroll
  for (int k = 0; k < 4; ++k) {
    const int idx = t + k * 512;     // 2048 = 64 rows x 32 cols
    const int row = idx >> 5;        // 0..63
    const int col = idx & 31;
    const int rh = row >> 5;
    const int rr = row & 31;
    const float v = (l_red[rh][0][rr][col] + l_red[rh][1][rr][col]) +
                    (l_red[rh][2][rr][col] + l_red[rh][3][rr][col]);
    out[(size_t)(row0 + row) * D_ + d0 + col] = v;
  }
}

extern "C" void kernel_launch(void* const* d_in, const int* in_sizes, int n_in,
                              void* d_out, int out_size, void* d_ws,
                              size_t ws_size, hipStream_t stream) {
  const float* M = (const float*)d_in[0];
  const int* mask = (const int*)d_in[1];
  const float* W1 = (const float*)d_in[2];
  const float* b1 = (const float*)d_in[3];
  const float* W2 = (const float*)d_in[4];
  const float* b2 = (const float*)d_in[5];
  const float* vw = (const float*)d_in[6];
  float* out = (float*)d_out;

  // workspace carve-up: ~18.25 MB total
  float* w1e = (float*)d_ws;                      // [2048][128] f32   1 MB
  ushort* w2eb = (ushort*)(w1e + 2048 * A_);      // [4][128][512] bf16 .5 MB
  ushort* ah = w2eb + 4 * A_ * N_;                // [2048][512] bf16  2 MB
  ushort* al = ah + 2048 * N_;                    //                   2 MB
  ushort* Mr_h = al + 2048 * N_;                  // [2048][768] bf16  3 MB
  ushort* Mr_l = Mr_h + 2048 * D_;                //                   3 MB
  ushort* Mt_h = Mr_l + 2048 * D_;                // [4][768][512]     3 MB
  ushort* Mt_l = Mt_h + 2048 * D_;                //                   3 MB
  ushort* Wt_h = Mt_l + 2048 * D_;                // [256][768] bf16   .375
  ushort* Wt_l = Wt_h + 256 * D_;                 //                   .375
  float* uvec = (float*)(Wt_l + 256 * D_);        // [128] f32         512B

  k0_prep<<<864, 256, 0, stream>>>(M, W1, W2, vw, Mr_h, Mr_l, Mt_h, Mt_l,
                                   Wt_h, Wt_l, uvec);
  k1_mfma<<<dim3(2048 / 32, 8), 512, 0, stream>>>(Mr_h, Mr_l, Wt_h, Wt_l,
                                                  b1, b2, w1e, w2eb);
  k2_scores<<<(B_ * N_) / 2, 512, 0, stream>>>(w1e, w2eb, uvec, mask, vw,
                                               ah, al);
  k3_mfma<<<dim3(2048 / 64, D_ / 32), 512, 0, stream>>>(ah, al, Mt_h, Mt_l,
                                                        out);
}

// Round 20
// 65.275 us; speedup vs baseline: 1.1114x; 1.1114x over previous
//
#include <hip/hip_runtime.h>

#define B_ 4
#define N_ 512
#define D_ 768
#define A_ 128

typedef short bf16x8 __attribute__((ext_vector_type(8)));
typedef ushort u16x8 __attribute__((ext_vector_type(8)));
typedef ushort u16x4 __attribute__((ext_vector_type(4)));
typedef float f32x4 __attribute__((ext_vector_type(4)));

__device__ __forceinline__ ushort f2h(float x) {  // f32 -> bf16 bits, RNE
  uint u = __builtin_bit_cast(uint, x);
  return (ushort)((u + 0x7fffu + ((u >> 16) & 1u)) >> 16);
}
__device__ __forceinline__ float h2f(ushort h) {
  uint u = ((uint)h) << 16;
  return __builtin_bit_cast(float, u);
}
__device__ __forceinline__ bf16x8 ld8(const ushort* p) {
  return *(const bf16x8*)p;
}
#define MFMA(a, b, c) __builtin_amdgcn_mfma_f32_16x16x32_bf16(a, b, c, 0, 0, 0)

// ---------------------------------------------------------------------------
// k0: fused prep (+ uvec = -2*v write). Unchanged from R18.
// ---------------------------------------------------------------------------
__global__ __launch_bounds__(256) void k0_prep(
    const float* __restrict__ M, const float* __restrict__ W1,
    const float* __restrict__ W2, const float* __restrict__ vw,
    ushort* __restrict__ Mr_h, ushort* __restrict__ Mr_l,
    ushort* __restrict__ Mt_h, ushort* __restrict__ Mt_l,
    ushort* __restrict__ Wt_h, ushort* __restrict__ Wt_l,
    float* __restrict__ uvec) {
  __shared__ ushort lds_h[64][40];
  __shared__ ushort lds_l[64][40];
  const int t = threadIdx.x;
  const int bid = blockIdx.x;
  if (bid < 768) {  // ---- M part ----
    const int dq = bid % 12;
    const int rest = bid / 12;
    const int d0 = dq * 64;
    const int n0 = (rest & 15) * 32;
    const int b = rest >> 4;
    const int n = t >> 3;          // 0..31
    const int dg = (t & 7) * 8;    // 0..56
    const size_t roff = ((size_t)(b * N_ + n0 + n)) * D_ + d0 + dg;
    const float4 v0 = *(const float4*)(M + roff);
    const float4 v1 = *(const float4*)(M + roff + 4);
    const float x[8] = {v0.x, v0.y, v0.z, v0.w, v1.x, v1.y, v1.z, v1.w};
    u16x8 vh, vl;
#pragma unroll
    for (int e = 0; e < 8; ++e) {
      ushort h = f2h(x[e]);
      ushort l = f2h(x[e] - h2f(h));
      vh[e] = h;
      vl[e] = l;
      lds_h[dg + e][n] = h;
      lds_l[dg + e][n] = l;
    }
    *(u16x8*)(Mr_h + roff) = vh;
    *(u16x8*)(Mr_l + roff) = vl;
    __syncthreads();
    const int dd = t >> 2;          // 0..63
    const int ng = (t & 3) * 8;     // 0..24
    const size_t toff = ((size_t)b * D_ + d0 + dd) * N_ + n0 + ng;
    *(u16x8*)(Mt_h + toff) = *(const u16x8*)(&lds_h[dd][ng]);
    *(u16x8*)(Mt_l + toff) = *(const u16x8*)(&lds_l[dd][ng]);
  } else {  // ---- W part ----
    const int c = t;
    const int k0 = (bid - 768) * 8;
    const float* __restrict__ Wp = (c < A_) ? W1 : W2;
    const int cc = c & (A_ - 1);
    u16x8 vh, vl;
#pragma unroll
    for (int e = 0; e < 8; ++e) {
      float x = Wp[(size_t)(k0 + e) * A_ + cc];
      ushort h = f2h(x);
      vh[e] = h;
      vl[e] = f2h(x - h2f(h));
    }
    *(u16x8*)(Wt_h + (size_t)c * D_ + k0) = vh;
    *(u16x8*)(Wt_l + (size_t)c * D_ + k0) = vl;
    if (bid == 768 && c < A_) uvec[c] = -2.f * vw[c];
  }
}

// ---------------------------------------------------------------------------
// k1 v4 (REVERT to R18 best): MFMA 3-pass, 4-wave K-split, register-prefetch
// double buffer. E1 f32 out; E2 bf16 out.
// ---------------------------------------------------------------------------
__global__ __launch_bounds__(256) void k1_mfma(
    const ushort* __restrict__ Mr_h, const ushort* __restrict__ Mr_l,
    const ushort* __restrict__ Wt_h, const ushort* __restrict__ Wt_l,
    const float* __restrict__ b1, const float* __restrict__ b2,
    float* __restrict__ w1e, ushort* __restrict__ w2e) {
  __shared__ float l_red[4][32][33];  // 16.9 KB
  const int t = threadIdx.x;
  const int l = t & 63;
  const int w = t >> 6;
  const int r = l & 15, g = l >> 4;
  const int row0 = blockIdx.x * 32;
  const int cb = blockIdx.y * 32;
  const int kbase = w * 192;  // wave-private K-range (6 K-steps of 32)
  const size_t oA = (size_t)(row0 + r) * D_ + kbase + g * 8;
  const size_t oA2 = oA + (size_t)16 * D_;
  const size_t oB = (size_t)(cb + r) * D_ + kbase + g * 8;
  const size_t oB2 = oB + (size_t)16 * D_;
  f32x4 acc[2][2] = {};
  bf16x8 A[2][4], Bv[2][4];
#define K1LOAD(s, k0)                                                        \
  A[s][0] = ld8(Mr_h + oA + (k0));  A[s][1] = ld8(Mr_h + oA2 + (k0));        \
  A[s][2] = ld8(Mr_l + oA + (k0));  A[s][3] = ld8(Mr_l + oA2 + (k0));        \
  Bv[s][0] = ld8(Wt_h + oB + (k0)); Bv[s][1] = ld8(Wt_h + oB2 + (k0));       \
  Bv[s][2] = ld8(Wt_l + oB + (k0)); Bv[s][3] = ld8(Wt_l + oB2 + (k0));
#define K1MM(s)                                                              \
  acc[0][0] = MFMA(A[s][0], Bv[s][0], acc[0][0]);                            \
  acc[0][0] = MFMA(A[s][0], Bv[s][2], acc[0][0]);                            \
  acc[0][0] = MFMA(A[s][2], Bv[s][0], acc[0][0]);                            \
  acc[0][1] = MFMA(A[s][0], Bv[s][1], acc[0][1]);                            \
  acc[0][1] = MFMA(A[s][0], Bv[s][3], acc[0][1]);                            \
  acc[0][1] = MFMA(A[s][2], Bv[s][1], acc[0][1]);                            \
  acc[1][0] = MFMA(A[s][1], Bv[s][0], acc[1][0]);                            \
  acc[1][0] = MFMA(A[s][1], Bv[s][2], acc[1][0]);                            \
  acc[1][0] = MFMA(A[s][3], Bv[s][0], acc[1][0]);                            \
  acc[1][1] = MFMA(A[s][1], Bv[s][1], acc[1][1]);                            \
  acc[1][1] = MFMA(A[s][1], Bv[s][3], acc[1][1]);                            \
  acc[1][1] = MFMA(A[s][3], Bv[s][1], acc[1][1]);
  K1LOAD(0, 0)
#pragma unroll
  for (int kt = 0; kt < 6; ++kt) {
    if (kt & 1) {
      if (kt < 5) { K1LOAD(0, (kt + 1) * 32) }
      K1MM(1)
    } else {
      if (kt < 5) { K1LOAD(1, (kt + 1) * 32) }
      K1MM(0)
    }
  }
#undef K1LOAD
#undef K1MM
#pragma unroll
  for (int fi = 0; fi < 2; ++fi)
#pragma unroll
    for (int fj = 0; fj < 2; ++fj)
#pragma unroll
      for (int rr = 0; rr < 4; ++rr)
        l_red[w][fi * 16 + g * 4 + rr][fj * 16 + r] = acc[fi][fj][rr];
  __syncthreads();

  const float SC = 2.8853900817779268f;  // 2*log2(e): e^{2x} = 2^{SC*x}
  const int b = row0 >> 9;
  const int n0 = row0 & (N_ - 1);
  if (cb < A_) {  // E1: w1e[row][col] f32, col-fast coalesced
#pragma unroll
    for (int k = 0; k < 4; ++k) {
      const int row = (t >> 5) + k * 8;
      const int col = t & 31;
      float v = l_red[0][row][col] + l_red[1][row][col] +
                l_red[2][row][col] + l_red[3][row][col];
      v = (v + b1[cb + col]) * SC;
      w1e[(size_t)(row0 + row) * A_ + cb + col] = __builtin_amdgcn_exp2f(v);
    }
  } else {  // E2: w2e[(b*128 + a)*512 + n] BF16, row(n)-fast
#pragma unroll
    for (int k = 0; k < 4; ++k) {
      const int row = t & 31;
      const int col = (t >> 5) + k * 8;
      float v = l_red[0][row][col] + l_red[1][row][col] +
                l_red[2][row][col] + l_red[3][row][col];
      v = (v + b2[cb - A_ + col]) * SC;
      w2e[(size_t)(b * A_ + cb - A_ + col) * N_ + n0 + row] =
          f2h(__builtin_amdgcn_exp2f(v));
    }
  }
}

// ---------------------------------------------------------------------------
// k2 v19: ROW-PAIRS — E2[a][j] is row-independent, so each wave owns TWO
// rows x one j-quarter: every E2 load + unpack is shared by both rows in
// registers. VMEM wave-instrs halve (1.05M -> 0.52M; the TA/L1 path was
// the largest pipe term). Barrier-free streaming as v18. Block 512 thr =
// 8 waves = 2 pairs x 4 quarters = 4 rows; grid 512 (2 blocks/CU,
// 4 waves/SIMD -- the proven regime). E1/u via scalar loads.
// ---------------------------------------------------------------------------
__global__ __launch_bounds__(512, 8) void k2_scores(
    const float* __restrict__ w1e, const ushort* __restrict__ w2e,
    const float* __restrict__ uvec, const int* __restrict__ mask,
    const float* __restrict__ vw, ushort* __restrict__ ah,
    ushort* __restrict__ al) {
  __shared__ float l_red[4][4];
  __shared__ float l_sum[4][4];
  const int t = threadIdx.x;
  const int lane = t & 63;
  const int w = t >> 6;   // 0..7
  const int p = w >> 2;   // row-pair in block 0..1
  const int q = w & 3;    // j-quarter
  const int i0 = blockIdx.x * 4;
  const int b = i0 >> 9;
  const int ib = __builtin_amdgcn_readfirstlane(i0 + p * 2);  // wave-uniform
  const float* __restrict__ w1r0 = w1e + (size_t)ib * A_;       // scalar
  const float* __restrict__ w1r1 = w1r0 + A_;                   // scalar

  float vs = vw[lane] + vw[64 + lane];  // Vsum via butterfly
#pragma unroll
  for (int off = 32; off; off >>= 1) vs += __shfl_xor(vs, off);

  const int jq = q * 128 + lane * 2;  // this lane's 2 j columns
  const ushort* __restrict__ w2p = w2e + (size_t)b * A_ * N_ + jq;

  float s0x = 0.f, s0y = 0.f;  // row ib,   j = jq, jq+1
  float s1x = 0.f, s1y = 0.f;  // row ib+1
#pragma unroll 1
  for (int cc = 0; cc < 8; ++cc) {
#pragma unroll 1
    for (int aa = 0; aa < 4; ++aa) {
      const float4 wa0 = *(const float4*)(w1r0 + cc * 16 + aa * 4);  // s_load
      const float4 wa1 = *(const float4*)(w1r1 + cc * 16 + aa * 4);  // s_load
      const float4 uu = *(const float4*)(uvec + cc * 16 + aa * 4);   // s_load
      const float wa0_[4] = {wa0.x, wa0.y, wa0.z, wa0.w};
      const float wa1_[4] = {wa1.x, wa1.y, wa1.z, wa1.w};
      const float uu_[4] = {uu.x, uu.y, uu.z, uu.w};
      uint xr_[4];
#pragma unroll
      for (int e = 0; e < 4; ++e)
        xr_[e] = *(const uint*)(w2p + (size_t)(cc * 16 + aa * 4 + e) * N_);
#pragma unroll
      for (int e = 0; e < 4; ++e) {
        const float ux = uu_[e];
        const float x0 = __builtin_bit_cast(float, xr_[e] << 16);
        const float x1 = __builtin_bit_cast(float, xr_[e] & 0xffff0000u);
        const float w0 = wa0_[e];
        const float w1 = wa1_[e];
        s0x = fmaf(ux, __builtin_amdgcn_rcpf(fmaf(w0, x0, 1.f)), s0x);
        s0y = fmaf(ux, __builtin_amdgcn_rcpf(fmaf(w0, x1, 1.f)), s0y);
        s1x = fmaf(ux, __builtin_amdgcn_rcpf(fmaf(w1, x0, 1.f)), s1x);
        s1y = fmaf(ux, __builtin_amdgcn_rcpf(fmaf(w1, x1, 1.f)), s1y);
      }
    }
  }

  // masks, then scores
  const float NEG = -3.402823466e38f;  // np.finfo(f32).min
  const int2 mk0 = *(const int2*)(mask + (size_t)ib * N_ + jq);
  const int2 mk1 = *(const int2*)(mask + (size_t)(ib + 1) * N_ + jq);
  s0x = mk0.x ? (vs + s0x) : NEG;
  s0y = mk0.y ? (vs + s0y) : NEG;
  s1x = mk1.x ? (vs + s1x) : NEG;
  s1y = mk1.y ? (vs + s1y) : NEG;

  // softmax: per-row wave max -> cross-quarter merge via LDS
  float m0 = fmaxf(s0x, s0y);
  float m1 = fmaxf(s1x, s1y);
#pragma unroll
  for (int off = 32; off; off >>= 1) {
    m0 = fmaxf(m0, __shfl_xor(m0, off));
    m1 = fmaxf(m1, __shfl_xor(m1, off));
  }
  if (lane == 0) {
    l_red[p * 2 + 0][q] = m0;
    l_red[p * 2 + 1][q] = m1;
  }
  __syncthreads();
  const float rmax0 = fmaxf(fmaxf(l_red[p * 2][0], l_red[p * 2][1]),
                            fmaxf(l_red[p * 2][2], l_red[p * 2][3]));
  const float rmax1 = fmaxf(fmaxf(l_red[p * 2 + 1][0], l_red[p * 2 + 1][1]),
                            fmaxf(l_red[p * 2 + 1][2], l_red[p * 2 + 1][3]));

  const float L2E = 1.4426950408889634f;
  // all-masked row: s-rmax = 0 -> 1 -> uniform 1/512 (ref match);
  // masked in live row: (NEG-rmax)*L2E -> -inf -> exp2 = 0 exactly.
  s0x = __builtin_amdgcn_exp2f((s0x - rmax0) * L2E);
  s0y = __builtin_amdgcn_exp2f((s0y - rmax0) * L2E);
  s1x = __builtin_amdgcn_exp2f((s1x - rmax1) * L2E);
  s1y = __builtin_amdgcn_exp2f((s1y - rmax1) * L2E);
  float ps0 = s0x + s0y;
  float ps1 = s1x + s1y;
#pragma unroll
  for (int off = 32; off; off >>= 1) {
    ps0 += __shfl_xor(ps0, off);
    ps1 += __shfl_xor(ps1, off);
  }
  if (lane == 0) {
    l_sum[p * 2 + 0][q] = ps0;
    l_sum[p * 2 + 1][q] = ps1;
  }
  __syncthreads();
  const float inv0 = __builtin_amdgcn_rcpf(
      (l_sum[p * 2][0] + l_sum[p * 2][1]) +
      (l_sum[p * 2][2] + l_sum[p * 2][3]));
  const float inv1 = __builtin_amdgcn_rcpf(
      (l_sum[p * 2 + 1][0] + l_sum[p * 2 + 1][1]) +
      (l_sum[p * 2 + 1][2] + l_sum[p * 2 + 1][3]));

  const float p0x = s0x * inv0, p0y = s0y * inv0;
  const float p1x = s1x * inv1, p1y = s1y * inv1;
  const ushort h0x = f2h(p0x), h0y = f2h(p0y);
  const ushort h1x = f2h(p1x), h1y = f2h(p1y);
  const ushort g0x = f2h(p0x - h2f(h0x)), g0y = f2h(p0y - h2f(h0y));
  const ushort g1x = f2h(p1x - h2f(h1x)), g1y = f2h(p1y - h2f(h1y));
  const size_t base0 = (size_t)ib * N_ + jq;
  const size_t base1 = base0 + N_;
  *(uint*)(ah + base0) = (uint)h0x | ((uint)h0y << 16);
  *(uint*)(al + base0) = (uint)g0x | ((uint)g0y << 16);
  *(uint*)(ah + base1) = (uint)h1x | ((uint)h1y << 16);
  *(uint*)(al + base1) = (uint)g1x | ((uint)g1y << 16);
}

// ---------------------------------------------------------------------------
// k3 v4 (REVERT to R18 best): 64x32 tiles, MFMA 3-pass, 4-wave j-split,
// register-prefetch pipeline, LDS reduce.
// ---------------------------------------------------------------------------
__global__ __launch_bounds__(256) void k3_mfma(
    const ushort* __restrict__ ah, const ushort* __restrict__ al,
    const ushort* __restrict__ Mt_h, const ushort* __restrict__ Mt_l,
    float* __restrict__ out) {
  __shared__ float l_red[4][64][33];  // 33.8 KB
  const int t = threadIdx.x;
  const int l = t & 63;
  const int w = t >> 6;
  const int r = l & 15, g = l >> 4;
  const int row0 = blockIdx.x * 64;    // global row b*N+i (64 | 512)
  const int d0 = blockIdx.y * 32;
  const int b = row0 >> 9;
  const int jbase = w * 128;  // wave-private j-range (4 K-steps of 32)
  const ushort* __restrict__ Bh = Mt_h + (size_t)b * D_ * N_;
  const ushort* __restrict__ Bl = Mt_l + (size_t)b * D_ * N_;
  size_t oA[4];
#pragma unroll
  for (int fi = 0; fi < 4; ++fi)
    oA[fi] = (size_t)(row0 + fi * 16 + r) * N_ + jbase + g * 8;
  const size_t oB = (size_t)(d0 + r) * N_ + jbase + g * 8;
  const size_t oB2 = oB + (size_t)16 * N_;
  f32x4 acc[4][2] = {};
  bf16x8 A[2][8], Bv[2][4];
#define K3LOAD(s, j0)                                                        \
  A[s][0] = ld8(ah + oA[0] + (j0)); A[s][1] = ld8(ah + oA[1] + (j0));        \
  A[s][2] = ld8(ah + oA[2] + (j0)); A[s][3] = ld8(ah + oA[3] + (j0));        \
  A[s][4] = ld8(al + oA[0] + (j0)); A[s][5] = ld8(al + oA[1] + (j0));        \
  A[s][6] = ld8(al + oA[2] + (j0)); A[s][7] = ld8(al + oA[3] + (j0));        \
  Bv[s][0] = ld8(Bh + oB + (j0));   Bv[s][1] = ld8(Bh + oB2 + (j0));         \
  Bv[s][2] = ld8(Bl + oB + (j0));   Bv[s][3] = ld8(Bl + oB2 + (j0));
#define K3MM(s)                                                              \
  _Pragma("unroll") for (int fi = 0; fi < 4; ++fi)                           \
  _Pragma("unroll") for (int fd = 0; fd < 2; ++fd) {                         \
    acc[fi][fd] = MFMA(A[s][fi], Bv[s][fd], acc[fi][fd]);                    \
    acc[fi][fd] = MFMA(A[s][fi], Bv[s][fd + 2], acc[fi][fd]);                \
    acc[fi][fd] = MFMA(A[s][fi + 4], Bv[s][fd], acc[fi][fd]);                \
  }
  K3LOAD(0, 0)
#pragma unroll
  for (int kt = 0; kt < 4; ++kt) {
    if (kt & 1) {
      if (kt < 3) { K3LOAD(0, (kt + 1) * 32) }
      K3MM(1)
    } else {
      if (kt < 3) { K3LOAD(1, (kt + 1) * 32) }
      K3MM(0)
    }
  }
#undef K3LOAD
#undef K3MM
#pragma unroll
  for (int fi = 0; fi < 4; ++fi)
#pragma unroll
    for (int fd = 0; fd < 2; ++fd)
#pragma unroll
      for (int rr = 0; rr < 4; ++rr)
        l_red[w][fi * 16 + g * 4 + rr][fd * 16 + r] = acc[fi][fd][rr];
  __syncthreads();
#pragma unroll
  for (int k = 0; k < 8; ++k) {
    const int row = (t >> 5) + k * 8;
    const int col = t & 31;
    const float v = l_red[0][row][col] + l_red[1][row][col] +
                    l_red[2][row][col] + l_red[3][row][col];
    out[(size_t)(row0 + row) * D_ + d0 + col] = v;
  }
}

extern "C" void kernel_launch(void* const* d_in, const int* in_sizes, int n_in,
                              void* d_out, int out_size, void* d_ws,
                              size_t ws_size, hipStream_t stream) {
  const float* M = (const float*)d_in[0];
  const int* mask = (const int*)d_in[1];
  const float* W1 = (const float*)d_in[2];
  const float* b1 = (const float*)d_in[3];
  const float* W2 = (const float*)d_in[4];
  const float* b2 = (const float*)d_in[5];
  const float* vw = (const float*)d_in[6];
  float* out = (float*)d_out;

  // workspace carve-up: ~18.25 MB total
  float* w1e = (float*)d_ws;                      // [2048][128] f32   1 MB
  ushort* w2eb = (ushort*)(w1e + 2048 * A_);      // [4][128][512] bf16 .5 MB
  ushort* ah = w2eb + 4 * A_ * N_;                // [2048][512] bf16  2 MB
  ushort* al = ah + 2048 * N_;                    //                   2 MB
  ushort* Mr_h = al + 2048 * N_;                  // [2048][768] bf16  3 MB
  ushort* Mr_l = Mr_h + 2048 * D_;                //                   3 MB
  ushort* Mt_h = Mr_l + 2048 * D_;                // [4][768][512]     3 MB
  ushort* Mt_l = Mt_h + 2048 * D_;                //                   3 MB
  ushort* Wt_h = Mt_l + 2048 * D_;                // [256][768] bf16   .375
  ushort* Wt_l = Wt_h + 256 * D_;                 //                   .375
  float* uvec = (float*)(Wt_l + 256 * D_);        // [128] f32         512B

  k0_prep<<<864, 256, 0, stream>>>(M, W1, W2, vw, Mr_h, Mr_l, Mt_h, Mt_l,
                                   Wt_h, Wt_l, uvec);
  k1_mfma<<<dim3(2048 / 32, 8), 256, 0, stream>>>(Mr_h, Mr_l, Wt_h, Wt_l,
                                                  b1, b2, w1e, w2eb);
  k2_scores<<<(B_ * N_) / 4, 512, 0, stream>>>(w1e, w2eb, uvec, mask, vw,
                                               ah, al);
  k3_mfma<<<dim3(2048 / 64, D_ / 32), 256, 0, stream>>>(ah, al, Mt_h, Mt_l,
                                                        out);
}

// Round 21
// 65.144 us; speedup vs baseline: 1.1136x; 1.0020x over previous
//
#include <hip/hip_runtime.h>

#define B_ 4
#define N_ 512
#define D_ 768
#define A_ 128

typedef short bf16x8 __attribute__((ext_vector_type(8)));
typedef ushort u16x8 __attribute__((ext_vector_type(8)));
typedef ushort u16x4 __attribute__((ext_vector_type(4)));
typedef float f32x4 __attribute__((ext_vector_type(4)));

__device__ __forceinline__ ushort f2h(float x) {  // f32 -> bf16 bits, RNE
  uint u = __builtin_bit_cast(uint, x);
  return (ushort)((u + 0x7fffu + ((u >> 16) & 1u)) >> 16);
}
__device__ __forceinline__ float h2f(ushort h) {
  uint u = ((uint)h) << 16;
  return __builtin_bit_cast(float, u);
}
__device__ __forceinline__ bf16x8 ld8(const ushort* p) {
  return *(const bf16x8*)p;
}
#define MFMA(a, b, c) __builtin_amdgcn_mfma_f32_16x16x32_bf16(a, b, c, 0, 0, 0)

// ---------------------------------------------------------------------------
// k0: fused prep (+ uvec = -2*v write). Unchanged from R20.
// ---------------------------------------------------------------------------
__global__ __launch_bounds__(256) void k0_prep(
    const float* __restrict__ M, const float* __restrict__ W1,
    const float* __restrict__ W2, const float* __restrict__ vw,
    ushort* __restrict__ Mr_h, ushort* __restrict__ Mr_l,
    ushort* __restrict__ Mt_h, ushort* __restrict__ Mt_l,
    ushort* __restrict__ Wt_h, ushort* __restrict__ Wt_l,
    float* __restrict__ uvec) {
  __shared__ ushort lds_h[64][40];
  __shared__ ushort lds_l[64][40];
  const int t = threadIdx.x;
  const int bid = blockIdx.x;
  if (bid < 768) {  // ---- M part ----
    const int dq = bid % 12;
    const int rest = bid / 12;
    const int d0 = dq * 64;
    const int n0 = (rest & 15) * 32;
    const int b = rest >> 4;
    const int n = t >> 3;          // 0..31
    const int dg = (t & 7) * 8;    // 0..56
    const size_t roff = ((size_t)(b * N_ + n0 + n)) * D_ + d0 + dg;
    const float4 v0 = *(const float4*)(M + roff);
    const float4 v1 = *(const float4*)(M + roff + 4);
    const float x[8] = {v0.x, v0.y, v0.z, v0.w, v1.x, v1.y, v1.z, v1.w};
    u16x8 vh, vl;
#pragma unroll
    for (int e = 0; e < 8; ++e) {
      ushort h = f2h(x[e]);
      ushort l = f2h(x[e] - h2f(h));
      vh[e] = h;
      vl[e] = l;
      lds_h[dg + e][n] = h;
      lds_l[dg + e][n] = l;
    }
    *(u16x8*)(Mr_h + roff) = vh;
    *(u16x8*)(Mr_l + roff) = vl;
    __syncthreads();
    const int dd = t >> 2;          // 0..63
    const int ng = (t & 3) * 8;     // 0..24
    const size_t toff = ((size_t)b * D_ + d0 + dd) * N_ + n0 + ng;
    *(u16x8*)(Mt_h + toff) = *(const u16x8*)(&lds_h[dd][ng]);
    *(u16x8*)(Mt_l + toff) = *(const u16x8*)(&lds_l[dd][ng]);
  } else {  // ---- W part ----
    const int c = t;
    const int k0 = (bid - 768) * 8;
    const float* __restrict__ Wp = (c < A_) ? W1 : W2;
    const int cc = c & (A_ - 1);
    u16x8 vh, vl;
#pragma unroll
    for (int e = 0; e < 8; ++e) {
      float x = Wp[(size_t)(k0 + e) * A_ + cc];
      ushort h = f2h(x);
      vh[e] = h;
      vl[e] = f2h(x - h2f(h));
    }
    *(u16x8*)(Wt_h + (size_t)c * D_ + k0) = vh;
    *(u16x8*)(Wt_l + (size_t)c * D_ + k0) = vl;
    if (bid == 768 && c < A_) uvec[c] = -2.f * vw[c];
  }
}

// ---------------------------------------------------------------------------
// k1 v4b: as R20 but GRID SWAPPED (x = col-tile, y = row-block) so
// consecutive block IDs share the same 32-row A-panel (L1/L2 locality).
// ---------------------------------------------------------------------------
__global__ __launch_bounds__(256) void k1_mfma(
    const ushort* __restrict__ Mr_h, const ushort* __restrict__ Mr_l,
    const ushort* __restrict__ Wt_h, const ushort* __restrict__ Wt_l,
    const float* __restrict__ b1, const float* __restrict__ b2,
    float* __restrict__ w1e, ushort* __restrict__ w2e) {
  __shared__ float l_red[4][32][33];  // 16.9 KB
  const int t = threadIdx.x;
  const int l = t & 63;
  const int w = t >> 6;
  const int r = l & 15, g = l >> 4;
  const int row0 = blockIdx.y * 32;   // swapped
  const int cb = blockIdx.x * 32;     // swapped: x fastest shares A-panel
  const int kbase = w * 192;  // wave-private K-range (6 K-steps of 32)
  const size_t oA = (size_t)(row0 + r) * D_ + kbase + g * 8;
  const size_t oA2 = oA + (size_t)16 * D_;
  const size_t oB = (size_t)(cb + r) * D_ + kbase + g * 8;
  const size_t oB2 = oB + (size_t)16 * D_;
  f32x4 acc[2][2] = {};
  bf16x8 A[2][4], Bv[2][4];
#define K1LOAD(s, k0)                                                        \
  A[s][0] = ld8(Mr_h + oA + (k0));  A[s][1] = ld8(Mr_h + oA2 + (k0));        \
  A[s][2] = ld8(Mr_l + oA + (k0));  A[s][3] = ld8(Mr_l + oA2 + (k0));        \
  Bv[s][0] = ld8(Wt_h + oB + (k0)); Bv[s][1] = ld8(Wt_h + oB2 + (k0));       \
  Bv[s][2] = ld8(Wt_l + oB + (k0)); Bv[s][3] = ld8(Wt_l + oB2 + (k0));
#define K1MM(s)                                                              \
  acc[0][0] = MFMA(A[s][0], Bv[s][0], acc[0][0]);                            \
  acc[0][0] = MFMA(A[s][0], Bv[s][2], acc[0][0]);                            \
  acc[0][0] = MFMA(A[s][2], Bv[s][0], acc[0][0]);                            \
  acc[0][1] = MFMA(A[s][0], Bv[s][1], acc[0][1]);                            \
  acc[0][1] = MFMA(A[s][0], Bv[s][3], acc[0][1]);                            \
  acc[0][1] = MFMA(A[s][2], Bv[s][1], acc[0][1]);                            \
  acc[1][0] = MFMA(A[s][1], Bv[s][0], acc[1][0]);                            \
  acc[1][0] = MFMA(A[s][1], Bv[s][2], acc[1][0]);                            \
  acc[1][0] = MFMA(A[s][3], Bv[s][0], acc[1][0]);                            \
  acc[1][1] = MFMA(A[s][1], Bv[s][1], acc[1][1]);                            \
  acc[1][1] = MFMA(A[s][1], Bv[s][3], acc[1][1]);                            \
  acc[1][1] = MFMA(A[s][3], Bv[s][1], acc[1][1]);
  K1LOAD(0, 0)
#pragma unroll
  for (int kt = 0; kt < 6; ++kt) {
    if (kt & 1) {
      if (kt < 5) { K1LOAD(0, (kt + 1) * 32) }
      K1MM(1)
    } else {
      if (kt < 5) { K1LOAD(1, (kt + 1) * 32) }
      K1MM(0)
    }
  }
#undef K1LOAD
#undef K1MM
#pragma unroll
  for (int fi = 0; fi < 2; ++fi)
#pragma unroll
    for (int fj = 0; fj < 2; ++fj)
#pragma unroll
      for (int rr = 0; rr < 4; ++rr)
        l_red[w][fi * 16 + g * 4 + rr][fj * 16 + r] = acc[fi][fj][rr];
  __syncthreads();

  const float SC = 2.8853900817779268f;  // 2*log2(e): e^{2x} = 2^{SC*x}
  const int b = row0 >> 9;
  const int n0 = row0 & (N_ - 1);
  if (cb < A_) {  // E1: w1e[row][col] f32, col-fast coalesced
#pragma unroll
    for (int k = 0; k < 4; ++k) {
      const int row = (t >> 5) + k * 8;
      const int col = t & 31;
      float v = l_red[0][row][col] + l_red[1][row][col] +
                l_red[2][row][col] + l_red[3][row][col];
      v = (v + b1[cb + col]) * SC;
      w1e[(size_t)(row0 + row) * A_ + cb + col] = __builtin_amdgcn_exp2f(v);
    }
  } else {  // E2: w2e[(b*128 + a)*512 + n] BF16, row(n)-fast
#pragma unroll
    for (int k = 0; k < 4; ++k) {
      const int row = t & 31;
      const int col = (t >> 5) + k * 8;
      float v = l_red[0][row][col] + l_red[1][row][col] +
                l_red[2][row][col] + l_red[3][row][col];
      v = (v + b2[cb - A_ + col]) * SC;
      w2e[(size_t)(b * A_ + cb - A_ + col) * N_ + n0 + row] =
          f2h(__builtin_amdgcn_exp2f(v));
    }
  }
}

// ---------------------------------------------------------------------------
// k2 v19b: row-pairs (R20 best) + vs folded into accumulator init.
// ---------------------------------------------------------------------------
__global__ __launch_bounds__(512, 8) void k2_scores(
    const float* __restrict__ w1e, const ushort* __restrict__ w2e,
    const float* __restrict__ uvec, const int* __restrict__ mask,
    const float* __restrict__ vw, ushort* __restrict__ ah,
    ushort* __restrict__ al) {
  __shared__ float l_red[4][4];
  __shared__ float l_sum[4][4];
  const int t = threadIdx.x;
  const int lane = t & 63;
  const int w = t >> 6;   // 0..7
  const int p = w >> 2;   // row-pair in block 0..1
  const int q = w & 3;    // j-quarter
  const int i0 = blockIdx.x * 4;
  const int b = i0 >> 9;
  const int ib = __builtin_amdgcn_readfirstlane(i0 + p * 2);  // wave-uniform
  const float* __restrict__ w1r0 = w1e + (size_t)ib * A_;       // scalar
  const float* __restrict__ w1r1 = w1r0 + A_;                   // scalar

  float vs = vw[lane] + vw[64 + lane];  // Vsum via butterfly
#pragma unroll
  for (int off = 32; off; off >>= 1) vs += __shfl_xor(vs, off);

  const int jq = q * 128 + lane * 2;  // this lane's 2 j columns
  const ushort* __restrict__ w2p = w2e + (size_t)b * A_ * N_ + jq;

  float s0x = vs, s0y = vs;  // row ib,   j = jq, jq+1 (vs pre-folded)
  float s1x = vs, s1y = vs;  // row ib+1
#pragma unroll 1
  for (int cc = 0; cc < 8; ++cc) {
#pragma unroll 1
    for (int aa = 0; aa < 4; ++aa) {
      const float4 wa0 = *(const float4*)(w1r0 + cc * 16 + aa * 4);  // s_load
      const float4 wa1 = *(const float4*)(w1r1 + cc * 16 + aa * 4);  // s_load
      const float4 uu = *(const float4*)(uvec + cc * 16 + aa * 4);   // s_load
      const float wa0_[4] = {wa0.x, wa0.y, wa0.z, wa0.w};
      const float wa1_[4] = {wa1.x, wa1.y, wa1.z, wa1.w};
      const float uu_[4] = {uu.x, uu.y, uu.z, uu.w};
      uint xr_[4];
#pragma unroll
      for (int e = 0; e < 4; ++e)
        xr_[e] = *(const uint*)(w2p + (size_t)(cc * 16 + aa * 4 + e) * N_);
#pragma unroll
      for (int e = 0; e < 4; ++e) {
        const float ux = uu_[e];
        const float x0 = __builtin_bit_cast(float, xr_[e] << 16);
        const float x1 = __builtin_bit_cast(float, xr_[e] & 0xffff0000u);
        const float w0 = wa0_[e];
        const float w1 = wa1_[e];
        s0x = fmaf(ux, __builtin_amdgcn_rcpf(fmaf(w0, x0, 1.f)), s0x);
        s0y = fmaf(ux, __builtin_amdgcn_rcpf(fmaf(w0, x1, 1.f)), s0y);
        s1x = fmaf(ux, __builtin_amdgcn_rcpf(fmaf(w1, x0, 1.f)), s1x);
        s1y = fmaf(ux, __builtin_amdgcn_rcpf(fmaf(w1, x1, 1.f)), s1y);
      }
    }
  }

  // masks, then scores
  const float NEG = -3.402823466e38f;  // np.finfo(f32).min
  const int2 mk0 = *(const int2*)(mask + (size_t)ib * N_ + jq);
  const int2 mk1 = *(const int2*)(mask + (size_t)(ib + 1) * N_ + jq);
  s0x = mk0.x ? s0x : NEG;
  s0y = mk0.y ? s0y : NEG;
  s1x = mk1.x ? s1x : NEG;
  s1y = mk1.y ? s1y : NEG;

  // softmax: per-row wave max -> cross-quarter merge via LDS
  float m0 = fmaxf(s0x, s0y);
  float m1 = fmaxf(s1x, s1y);
#pragma unroll
  for (int off = 32; off; off >>= 1) {
    m0 = fmaxf(m0, __shfl_xor(m0, off));
    m1 = fmaxf(m1, __shfl_xor(m1, off));
  }
  if (lane == 0) {
    l_red[p * 2 + 0][q] = m0;
    l_red[p * 2 + 1][q] = m1;
  }
  __syncthreads();
  const float rmax0 = fmaxf(fmaxf(l_red[p * 2][0], l_red[p * 2][1]),
                            fmaxf(l_red[p * 2][2], l_red[p * 2][3]));
  const float rmax1 = fmaxf(fmaxf(l_red[p * 2 + 1][0], l_red[p * 2 + 1][1]),
                            fmaxf(l_red[p * 2 + 1][2], l_red[p * 2 + 1][3]));

  const float L2E = 1.4426950408889634f;
  // all-masked row: s-rmax = 0 -> 1 -> uniform 1/512 (ref match);
  // masked in live row: (NEG-rmax)*L2E -> -inf -> exp2 = 0 exactly.
  s0x = __builtin_amdgcn_exp2f((s0x - rmax0) * L2E);
  s0y = __builtin_amdgcn_exp2f((s0y - rmax0) * L2E);
  s1x = __builtin_amdgcn_exp2f((s1x - rmax1) * L2E);
  s1y = __builtin_amdgcn_exp2f((s1y - rmax1) * L2E);
  float ps0 = s0x + s0y;
  float ps1 = s1x + s1y;
#pragma unroll
  for (int off = 32; off; off >>= 1) {
    ps0 += __shfl_xor(ps0, off);
    ps1 += __shfl_xor(ps1, off);
  }
  if (lane == 0) {
    l_sum[p * 2 + 0][q] = ps0;
    l_sum[p * 2 + 1][q] = ps1;
  }
  __syncthreads();
  const float inv0 = __builtin_amdgcn_rcpf(
      (l_sum[p * 2][0] + l_sum[p * 2][1]) +
      (l_sum[p * 2][2] + l_sum[p * 2][3]));
  const float inv1 = __builtin_amdgcn_rcpf(
      (l_sum[p * 2 + 1][0] + l_sum[p * 2 + 1][1]) +
      (l_sum[p * 2 + 1][2] + l_sum[p * 2 + 1][3]));

  const float p0x = s0x * inv0, p0y = s0y * inv0;
  const float p1x = s1x * inv1, p1y = s1y * inv1;
  const ushort h0x = f2h(p0x), h0y = f2h(p0y);
  const ushort h1x = f2h(p1x), h1y = f2h(p1y);
  const ushort g0x = f2h(p0x - h2f(h0x)), g0y = f2h(p0y - h2f(h0y));
  const ushort g1x = f2h(p1x - h2f(h1x)), g1y = f2h(p1y - h2f(h1y));
  const size_t base0 = (size_t)ib * N_ + jq;
  const size_t base1 = base0 + N_;
  *(uint*)(ah + base0) = (uint)h0x | ((uint)h0y << 16);
  *(uint*)(al + base0) = (uint)g0x | ((uint)g0y << 16);
  *(uint*)(ah + base1) = (uint)h1x | ((uint)h1y << 16);
  *(uint*)(al + base1) = (uint)g1x | ((uint)g1y << 16);
}

// ---------------------------------------------------------------------------
// k3 v4b: as R20 but GRID SWAPPED (x = d-block, y = row-block) so
// consecutive block IDs share the same 64-row A-panel (L1/L2 locality).
// ---------------------------------------------------------------------------
__global__ __launch_bounds__(256) void k3_mfma(
    const ushort* __restrict__ ah, const ushort* __restrict__ al,
    const ushort* __restrict__ Mt_h, const ushort* __restrict__ Mt_l,
    float* __restrict__ out) {
  __shared__ float l_red[4][64][33];  // 33.8 KB
  const int t = threadIdx.x;
  const int l = t & 63;
  const int w = t >> 6;
  const int r = l & 15, g = l >> 4;
  const int row0 = blockIdx.y * 64;   // swapped
  const int d0 = blockIdx.x * 32;     // swapped: x fastest shares A-panel
  const int b = row0 >> 9;
  const int jbase = w * 128;  // wave-private j-range (4 K-steps of 32)
  const ushort* __restrict__ Bh = Mt_h + (size_t)b * D_ * N_;
  const ushort* __restrict__ Bl = Mt_l + (size_t)b * D_ * N_;
  size_t oA[4];
#pragma unroll
  for (int fi = 0; fi < 4; ++fi)
    oA[fi] = (size_t)(row0 + fi * 16 + r) * N_ + jbase + g * 8;
  const size_t oB = (size_t)(d0 + r) * N_ + jbase + g * 8;
  const size_t oB2 = oB + (size_t)16 * N_;
  f32x4 acc[4][2] = {};
  bf16x8 A[2][8], Bv[2][4];
#define K3LOAD(s, j0)                                                        \
  A[s][0] = ld8(ah + oA[0] + (j0)); A[s][1] = ld8(ah + oA[1] + (j0));        \
  A[s][2] = ld8(ah + oA[2] + (j0)); A[s][3] = ld8(ah + oA[3] + (j0));        \
  A[s][4] = ld8(al + oA[0] + (j0)); A[s][5] = ld8(al + oA[1] + (j0));        \
  A[s][6] = ld8(al + oA[2] + (j0)); A[s][7] = ld8(al + oA[3] + (j0));        \
  Bv[s][0] = ld8(Bh + oB + (j0));   Bv[s][1] = ld8(Bh + oB2 + (j0));         \
  Bv[s][2] = ld8(Bl + oB + (j0));   Bv[s][3] = ld8(Bl + oB2 + (j0));
#define K3MM(s)                                                              \
  _Pragma("unroll") for (int fi = 0; fi < 4; ++fi)                           \
  _Pragma("unroll") for (int fd = 0; fd < 2; ++fd) {                         \
    acc[fi][fd] = MFMA(A[s][fi], Bv[s][fd], acc[fi][fd]);                    \
    acc[fi][fd] = MFMA(A[s][fi], Bv[s][fd + 2], acc[fi][fd]);                \
    acc[fi][fd] = MFMA(A[s][fi + 4], Bv[s][fd], acc[fi][fd]);                \
  }
  K3LOAD(0, 0)
#pragma unroll
  for (int kt = 0; kt < 4; ++kt) {
    if (kt & 1) {
      if (kt < 3) { K3LOAD(0, (kt + 1) * 32) }
      K3MM(1)
    } else {
      if (kt < 3) { K3LOAD(1, (kt + 1) * 32) }
      K3MM(0)
    }
  }
#undef K3LOAD
#undef K3MM
#pragma unroll
  for (int fi = 0; fi < 4; ++fi)
#pragma unroll
    for (int fd = 0; fd < 2; ++fd)
#pragma unroll
      for (int rr = 0; rr < 4; ++rr)
        l_red[w][fi * 16 + g * 4 + rr][fd * 16 + r] = acc[fi][fd][rr];
  __syncthreads();
#pragma unroll
  for (int k = 0; k < 8; ++k) {
    const int row = (t >> 5) + k * 8;
    const int col = t & 31;
    const float v = l_red[0][row][col] + l_red[1][row][col] +
                    l_red[2][row][col] + l_red[3][row][col];
    out[(size_t)(row0 + row) * D_ + d0 + col] = v;
  }
}

extern "C" void kernel_launch(void* const* d_in, const int* in_sizes, int n_in,
                              void* d_out, int out_size, void* d_ws,
                              size_t ws_size, hipStream_t stream) {
  const float* M = (const float*)d_in[0];
  const int* mask = (const int*)d_in[1];
  const float* W1 = (const float*)d_in[2];
  const float* b1 = (const float*)d_in[3];
  const float* W2 = (const float*)d_in[4];
  const float* b2 = (const float*)d_in[5];
  const float* vw = (const float*)d_in[6];
  float* out = (float*)d_out;

  // workspace carve-up: ~18.25 MB total
  float* w1e = (float*)d_ws;                      // [2048][128] f32   1 MB
  ushort* w2eb = (ushort*)(w1e + 2048 * A_);      // [4][128][512] bf16 .5 MB
  ushort* ah = w2eb + 4 * A_ * N_;                // [2048][512] bf16  2 MB
  ushort* al = ah + 2048 * N_;                    //                   2 MB
  ushort* Mr_h = al + 2048 * N_;                  // [2048][768] bf16  3 MB
  ushort* Mr_l = Mr_h + 2048 * D_;                //                   3 MB
  ushort* Mt_h = Mr_l + 2048 * D_;                // [4][768][512]     3 MB
  ushort* Mt_l = Mt_h + 2048 * D_;                //                   3 MB
  ushort* Wt_h = Mt_l + 2048 * D_;                // [256][768] bf16   .375
  ushort* Wt_l = Wt_h + 256 * D_;                 //                   .375
  float* uvec = (float*)(Wt_l + 256 * D_);        // [128] f32         512B

  k0_prep<<<864, 256, 0, stream>>>(M, W1, W2, vw, Mr_h, Mr_l, Mt_h, Mt_l,
                                   Wt_h, Wt_l, uvec);
  k1_mfma<<<dim3(8, 2048 / 32), 256, 0, stream>>>(Mr_h, Mr_l, Wt_h, Wt_l,
                                                  b1, b2, w1e, w2eb);
  k2_scores<<<(B_ * N_) / 4, 512, 0, stream>>>(w1e, w2eb, uvec, mask, vw,
                                               ah, al);
  k3_mfma<<<dim3(D_ / 32, 2048 / 64), 256, 0, stream>>>(ah, al, Mt_h, Mt_l,
                                                        out);
}